// Round 10
// baseline (100.816 us; speedup 1.0000x reference)
//
#include <hip/hip_runtime.h>
#include <math.h>

// Sliding-window (n=64) temperature-softmax attention, fp32, N=4194304.
// ROUND 10 = TWO-ARM INSTRUMENTED ABLATION (both arms >45us -> counter-visible):
//   K1: exact R9 body x REP=4 -> d_out (correct).  Reads VGPR/VALUBusy/exec-per-rep.
//   K2: same body x REP=7, exp2 replaced by 2-VALU FMA stub (same deps, no trans
//       pipe) -> d_ws.  K2/7 vs K1/4 isolates the transcendental-pipe share.

#define SEG 32
#define BLK 256
#define ROWS (BLK + 2)        // 258 segments: [S0-2, S0+255]
#define RSTRIDE 36            // 32 data + 4 pad floats
#define PADV -1.0e30f

typedef float f32x32 __attribute__((ext_vector_type(32)));

__device__ __forceinline__ float fexp2(float x) { return __builtin_amdgcn_exp2f(x); }

template<int REPS, bool REAL>
__global__ __launch_bounds__(256) void sa_kernel(
    const float* __restrict__ x_in, const float* __restrict__ w_tau,
    float* __restrict__ out_in)
{
    __shared__ float lds[ROWS * RSTRIDE];   // 37152 B

    const int tid = threadIdx.x;
    const int S0  = blockIdx.x * BLK;
    const int s   = S0 + tid;

    unsigned long long xa = (unsigned long long)(uintptr_t)x_in;
    unsigned long long oa = (unsigned long long)(uintptr_t)out_in;

#pragma unroll 1
    for (int rep = 0; rep < REPS; ++rep) {
        asm volatile("" : "+s"(xa), "+s"(oa) :: "memory");
        const float* __restrict__ x = (const float*)(uintptr_t)xa;
        float* __restrict__ out = (float*)(uintptr_t)oa;

        const float tau = log1pf(expf(w_tau[0])) + 1e-5f;
        const float C = 1.4426950408889634f / tau;

        // ---- Stage segments [S0-2, S0+255] into LDS, coalesced.
        {
            const int base4 = (S0 - 2) * (SEG / 4);
#pragma unroll
            for (int it = 0; it < 9; ++it) {
                const int i = tid + it * BLK;
                if (i < ROWS * (SEG / 4)) {
                    const int g4 = base4 + i;
                    float4 t;
                    if (g4 >= 0) t = reinterpret_cast<const float4*>(x)[g4];
                    else         t = make_float4(PADV, PADV, PADV, PADV);
                    const int r = i >> 3, c = i & 7;
                    *reinterpret_cast<float4*>(&lds[r * RSTRIDE + c * 4]) = t;
                }
            }
        }
        __syncthreads();

        // EFN: exp2 (real) or same-dependency 2-VALU stub (ablation arm).
#define EFN(d) (REAL ? fexp2(d) : fmaf((d), 3.0e-7f, 0.5f))
#define STEP(val, M, R0, R1)                                   \
        {                                                      \
            const float _v = (val);                            \
            const float _d = -fabsf((M) - _v) * C;             \
            const float _e = EFN(_d);                          \
            const float _ea = (_v >= (M)) ? 1.f : _e;          \
            const float _eb = (_v >= (M)) ? _e : 1.f;          \
            (R0) = (R0) * _eb + _ea;                           \
            (R1) = (R1) * _eb + _v * _ea;                      \
            (M) = fmaxf((M), _v);                              \
        }

        // ---- Suffix scan over seg s-2 (LDS row tid), backwards.
        f32x32 Sm, Sa, Sb;
        {
            const float* row0 = &lds[tid * RSTRIDE];
            float sm = PADV, sa = 0.f, sb = 0.f;
            Sm[31] = PADV; Sa[31] = 0.f; Sb[31] = 0.f;
#pragma unroll
            for (int c = 7; c >= 0; --c) {
                const float4 t = *reinterpret_cast<const float4*>(row0 + 4 * c);
                STEP(t.w, sm, sa, sb); Sm[4*c+2] = sm; Sa[4*c+2] = sa; Sb[4*c+2] = sb;
                STEP(t.z, sm, sa, sb); Sm[4*c+1] = sm; Sa[4*c+1] = sa; Sb[4*c+1] = sb;
                STEP(t.y, sm, sa, sb); Sm[4*c+0] = sm; Sa[4*c+0] = sa; Sb[4*c+0] = sb;
                if (c > 0) { STEP(t.x, sm, sa, sb); Sm[4*c-1] = sm; Sa[4*c-1] = sa; Sb[4*c-1] = sb; }
            }
        }

        // ---- Prefix scan over seg s-1 (LDS row tid+1).
        float m = PADV, r0 = 0.f, r1 = 0.f;
        {
            const float* row1 = &lds[(tid + 1) * RSTRIDE];
#pragma unroll
            for (int c = 0; c < 8; ++c) {
                const float4 t = *reinterpret_cast<const float4*>(row1 + 4 * c);
                STEP(t.x, m, r0, r1); STEP(t.y, m, r0, r1);
                STEP(t.z, m, r0, r1); STEP(t.w, m, r0, r1);
            }
        }

        // ---- Emission over seg s (LDS row tid+2).
        const float* row2 = &lds[(tid + 2) * RSTRIDE];
        float4* o4 = reinterpret_cast<float4*>(out + (size_t)s * SEG);
#pragma unroll
        for (int c = 0; c < 8; ++c) {
            const float4 t = *reinterpret_cast<const float4*>(row2 + 4 * c);
            float4 ob;
#pragma unroll
            for (int j = 0; j < 4; ++j) {
                const int p = 4 * c + j;
                const float val = (j == 0) ? t.x : (j == 1) ? t.y : (j == 2) ? t.z : t.w;
                STEP(val, m, r0, r1);
                const float smv = Sm[p];
                const float _dc = -fabsf(m - smv) * C;
                const float ec  = EFN(_dc);
                const float e1  = (m >= smv) ? 1.f : ec;
                const float e2  = (m >= smv) ? ec : 1.f;
                const float t0  = r0 * e1 + Sa[p] * e2;
                const float t1  = r1 * e1 + Sb[p] * e2;
                const float res = t1 * __builtin_amdgcn_rcpf(t0);
                if      (j == 0) ob.x = res;
                else if (j == 1) ob.y = res;
                else if (j == 2) ob.z = res;
                else             ob.w = res;
            }
            o4[c] = ob;
        }
#undef STEP
#undef EFN
        __syncthreads();   // LDS WAR guard before next rep's staging
    }
}

extern "C" void kernel_launch(void* const* d_in, const int* in_sizes, int n_in,
                              void* d_out, int out_size, void* d_ws, size_t ws_size,
                              hipStream_t stream) {
    const float* x = (const float*)d_in[0];
    const float* w = (const float*)d_in[1];
    float* outp = (float*)d_out;
    const int N = in_sizes[0];                 // 4194304
    const int nseg = N / SEG;                  // 131072
    const int blocks = nseg / BLK;             // 512

    // K1: real math, REP=4, correct output (last rep rewrites d_out idempotently).
    sa_kernel<4, true><<<blocks, BLK, 0, stream>>>(x, w, outp);

    // K2: trans-pipe ablation, REP=7, writes garbage (deterministic) to d_ws.
    if (ws_size >= (size_t)N * sizeof(float)) {
        sa_kernel<7, false><<<blocks, BLK, 0, stream>>>(x, w, (float*)d_ws);
    }
}

// Round 11
// 17.879 us; speedup vs baseline: 5.6389x; 5.6389x over previous
//
#include <hip/hip_runtime.h>
#include <math.h>

// Sliding-window (n=64) temperature-softmax attention, fp32, N=4194304.
// Round 11: u-domain scan. R10's ablation proved: trans pipe ~free (stub arm
// SLOWER than real exp2 arm), core is VALU-issue-bound (~7us warm, VALUBusy 61%).
// So: pre-scale u = v*C at staging (stored scaled in LDS) and use the
// cndmask-free 2-exp STEP: 6 VALU + 2 trans (was 9 VALU + 1 trans).
// Weighted mean computed in u-domain, rescaled by tau*ln2 once per output.

#define SEG 32
#define BLK 256
#define ROWS (BLK + 2)        // 258 segments: [S0-2, S0+255]
#define RSTRIDE 36            // 32 data + 4 pad floats (144B rows, 16B-aligned)
#define PADU -3.0e34f         // u-domain pad: exp2(PADU - real) == 0 exactly

typedef float f32x32 __attribute__((ext_vector_type(32)));

__device__ __forceinline__ float fexp2(float x) { return __builtin_amdgcn_exp2f(x); }

__global__ __launch_bounds__(256) void soft_attn_kernel(
    const float* __restrict__ x, const float* __restrict__ w_tau,
    float* __restrict__ out)
{
    __shared__ float lds[ROWS * RSTRIDE];   // 37152 B

    const int tid = threadIdx.x;
    const int S0  = blockIdx.x * BLK;       // first owned segment of this block
    const int s   = S0 + tid;               // this thread's segment

    const float tau  = log1pf(expf(w_tau[0])) + 1e-5f;
    const float C    = 1.4426950408889634f / tau;   // log2(e)/tau
    const float invC = 0.6931471805599453f * tau;   // 1/C

    // ---- Stage segments [S0-2, S0+255] into LDS, coalesced, PRE-SCALED by C.
    {
        const float4* x4 = reinterpret_cast<const float4*>(x);
        const int base4 = (S0 - 2) * (SEG / 4);
#pragma unroll
        for (int it = 0; it < 9; ++it) {
            const int i = tid + it * BLK;            // float4 index in region
            if (it < 8 || i < ROWS * (SEG / 4)) {    // tail: only 16 lanes
                const int g4 = base4 + i;
                float4 t;
                if (g4 >= 0) {                       // uniform-true for blocks > 0
                    t = x4[g4];
                    t.x *= C; t.y *= C; t.z *= C; t.w *= C;
                } else {
                    t = make_float4(PADU, PADU, PADU, PADU);
                }
                const int r = i >> 3, c = i & 7;
                *reinterpret_cast<float4*>(&lds[r * RSTRIDE + c * 4]) = t;
            }
        }
    }
    __syncthreads();

    // u-domain online-softmax append: 6 VALU + 2 trans, no compare/cndmask.
    // One of (_ea,_eb) is exp2(0)=1; trans issues overlap the VALU stream.
#define STEP(u_, M, R0, R1)                                    \
    {                                                          \
        const float _u  = (u_);                                \
        const float _nm = fmaxf((M), _u);                      \
        const float _ea = fexp2(_u - _nm);                     \
        const float _eb = fexp2((M) - _nm);                    \
        (R0) = (R0) * _eb + _ea;                               \
        (R1) = (R1) * _eb + _u * _ea;                          \
        (M)  = _nm;                                            \
    }

    // ---- Suffix scan over seg s-2 (LDS row tid), backwards.
    // Slot p holds scan of elements [p+1 .. 31]; slot 31 = empty.
    f32x32 Sm, Sa, Sb;
    {
        const float* row0 = &lds[tid * RSTRIDE];
        float sm = PADU, sa = 0.f, sb = 0.f;
        Sm[31] = PADU; Sa[31] = 0.f; Sb[31] = 0.f;
#pragma unroll
        for (int c = 7; c >= 0; --c) {
            const float4 t = *reinterpret_cast<const float4*>(row0 + 4 * c);
            STEP(t.w, sm, sa, sb); Sm[4*c+2] = sm; Sa[4*c+2] = sa; Sb[4*c+2] = sb;
            STEP(t.z, sm, sa, sb); Sm[4*c+1] = sm; Sa[4*c+1] = sa; Sb[4*c+1] = sb;
            STEP(t.y, sm, sa, sb); Sm[4*c+0] = sm; Sa[4*c+0] = sa; Sb[4*c+0] = sb;
            if (c > 0) { STEP(t.x, sm, sa, sb); Sm[4*c-1] = sm; Sa[4*c-1] = sa; Sb[4*c-1] = sb; }
        }
    }

    // ---- Prefix scan over seg s-1 (LDS row tid+1), full 32 elements.
    float m = PADU, r0 = 0.f, r1 = 0.f;
    {
        const float* row1 = &lds[(tid + 1) * RSTRIDE];
#pragma unroll
        for (int c = 0; c < 8; ++c) {
            const float4 t = *reinterpret_cast<const float4*>(row1 + 4 * c);
            STEP(t.x, m, r0, r1); STEP(t.y, m, r0, r1);
            STEP(t.z, m, r0, r1); STEP(t.w, m, r0, r1);
        }
    }

    // ---- Emission over seg s (LDS row tid+2): continue prefix, combine with suffix.
    const float* row2 = &lds[(tid + 2) * RSTRIDE];
    float4* o4 = reinterpret_cast<float4*>(out + (size_t)s * SEG);
#pragma unroll
    for (int c = 0; c < 8; ++c) {
        const float4 t = *reinterpret_cast<const float4*>(row2 + 4 * c);
        float4 ob;
#pragma unroll
        for (int j = 0; j < 4; ++j) {
            const int p = 4 * c + j;
            const float u = (j == 0) ? t.x : (j == 1) ? t.y : (j == 2) ? t.z : t.w;
            STEP(u, m, r0, r1);
            // combine running prefix (m,r0,r1) with suffix triple at p
            const float smv = Sm[p];
            const float mm  = fmaxf(m, smv);
            const float e1  = fexp2(m   - mm);
            const float e2  = fexp2(smv - mm);
            const float t0  = fmaf(r0, e1, Sa[p] * e2);
            const float t1  = fmaf(r1, e1, Sb[p] * e2);
            const float res = t1 * __builtin_amdgcn_rcpf(t0) * invC;  // t0 in [1,64]
            if      (j == 0) ob.x = res;
            else if (j == 1) ob.y = res;
            else if (j == 2) ob.z = res;
            else             ob.w = res;
        }
        o4[c] = ob;
    }
#undef STEP
}

extern "C" void kernel_launch(void* const* d_in, const int* in_sizes, int n_in,
                              void* d_out, int out_size, void* d_ws, size_t ws_size,
                              hipStream_t stream) {
    const float* x = (const float*)d_in[0];
    const float* w = (const float*)d_in[1];
    float* outp = (float*)d_out;
    const int N = in_sizes[0];                 // 4194304
    const int nseg = N / SEG;                  // 131072
    const int blocks = nseg / BLK;             // 512
    soft_attn_kernel<<<blocks, BLK, 0, stream>>>(x, w, outp);
}